// Round 1
// baseline (616.962 us; speedup 1.0000x reference)
//
#include <hip/hip_runtime.h>
#include <math.h>

#define BB 64
#define SS 2048
#define HH 512
#define AA 128
#define MM (BB*SS)

// ---------------------------------------------------------------------------
// Kernel 1: scores[m] = tanh(X[m,:] @ W1 + b1) @ W2 + b2
// Tiled fp32 GEMM: 128 rows/block, full N=128, BK=32, fused tanh+dot epilogue.
// ---------------------------------------------------------------------------
__global__ __launch_bounds__(256) void score_kernel(
    const float* __restrict__ X, const float* __restrict__ W1,
    const float* __restrict__ b1, const float* __restrict__ W2,
    const float* __restrict__ b2, float* __restrict__ scores)
{
    __shared__ float As[32][129];   // A tile transposed: [k][row], +1 pad
    __shared__ float Bs[32][128];   // W1 tile: [k][col]
    const int tid = threadIdx.x;
    const int tr = tid >> 4;        // 0..15 -> rows tr*8..tr*8+7
    const int tc = tid & 15;        // 0..15 -> cols tc*8..tc*8+7
    const int m0 = blockIdx.x * 128;

    float acc[8][8];
    #pragma unroll
    for (int i = 0; i < 8; i++)
        #pragma unroll
        for (int j = 0; j < 8; j++) acc[i][j] = 0.f;

    for (int k0 = 0; k0 < HH; k0 += 32) {
        // Stage A tile (128 rows x 32 k), transposed into LDS
        #pragma unroll
        for (int i = 0; i < 4; i++) {
            int v = tid + 256 * i;            // 0..1023 float4 slots
            int row = v >> 3;                 // 0..127
            int c4  = (v & 7) << 2;           // 0..28
            float4 f = *(const float4*)(X + (size_t)(m0 + row) * HH + k0 + c4);
            As[c4 + 0][row] = f.x;
            As[c4 + 1][row] = f.y;
            As[c4 + 2][row] = f.z;
            As[c4 + 3][row] = f.w;
        }
        // Stage W1 tile (32 k x 128 cols)
        #pragma unroll
        for (int i = 0; i < 4; i++) {
            int v = tid + 256 * i;
            int row = v >> 5;                 // 0..31
            int c4  = (v & 31) << 2;          // 0..124
            *(float4*)&Bs[row][c4] =
                *(const float4*)(W1 + (size_t)(k0 + row) * AA + c4);
        }
        __syncthreads();
        #pragma unroll
        for (int k = 0; k < 32; k++) {
            float a[8], bb[8];
            *(float4*)&a[0]  = *(float4*)&As[k][tr * 8];
            *(float4*)&a[4]  = *(float4*)&As[k][tr * 8 + 4];
            *(float4*)&bb[0] = *(float4*)&Bs[k][tc * 8];
            *(float4*)&bb[4] = *(float4*)&Bs[k][tc * 8 + 4];
            #pragma unroll
            for (int i = 0; i < 8; i++)
                #pragma unroll
                for (int j = 0; j < 8; j++)
                    acc[i][j] = fmaf(a[i], bb[j], acc[i][j]);
        }
        __syncthreads();
    }

    // Epilogue: tanh + dot with W2, reduce across the 16 col-threads
    float part[8];
    #pragma unroll
    for (int i = 0; i < 8; i++) part[i] = 0.f;
    #pragma unroll
    for (int j = 0; j < 8; j++) {
        int c = tc * 8 + j;
        float bias = b1[c];
        float w2   = W2[c];
        #pragma unroll
        for (int i = 0; i < 8; i++)
            part[i] += tanhf(acc[i][j] + bias) * w2;
    }
    #pragma unroll
    for (int off = 8; off > 0; off >>= 1)
        #pragma unroll
        for (int i = 0; i < 8; i++)
            part[i] += __shfl_down(part[i], off, 16);
    if (tc == 0) {
        float bb2 = b2[0];
        #pragma unroll
        for (int i = 0; i < 8; i++)
            scores[m0 + tr * 8 + i] = part[i] + bb2;
    }
}

// ---------------------------------------------------------------------------
// Kernel 2: exact entmax-1.5 over S=2048 per batch (one block per batch).
// scores may alias the weights output: fully read before any write.
// ---------------------------------------------------------------------------
__global__ __launch_bounds__(1024) void entmax_kernel(
    const float* __restrict__ scores, float* __restrict__ weights)
{
    __shared__ float s_orig[SS];
    __shared__ float srt[SS];
    __shared__ float tau[SS];
    __shared__ float sp[1024];
    __shared__ float sq[1024];
    __shared__ float red[16];
    __shared__ int   s_cnt;
    __shared__ float s_max, s_taustar;

    const int t = threadIdx.x;
    const int b = blockIdx.x;
    const float* row = scores + (size_t)b * SS;

    float v0 = row[t];
    float v1 = row[t + 1024];

    // block max
    float mx = fmaxf(v0, v1);
    #pragma unroll
    for (int off = 32; off > 0; off >>= 1)
        mx = fmaxf(mx, __shfl_down(mx, off, 64));
    if ((t & 63) == 0) red[t >> 6] = mx;
    __syncthreads();
    if (t < 16) {
        float m = red[t];
        #pragma unroll
        for (int off = 8; off > 0; off >>= 1)
            m = fmaxf(m, __shfl_down(m, off, 16));
        if (t == 0) s_max = m;
    }
    __syncthreads();
    mx = s_max;
    v0 = (v0 - mx) * 0.5f;
    v1 = (v1 - mx) * 0.5f;
    s_orig[t]        = v0;
    s_orig[t + 1024] = v1;
    srt[t]           = v0;
    srt[t + 1024]    = v1;
    __syncthreads();

    // bitonic sort, descending
    for (int k = 2; k <= SS; k <<= 1) {
        for (int j = k >> 1; j > 0; j >>= 1) {
            #pragma unroll
            for (int u = 0; u < 2; u++) {
                int i = t + 1024 * u;
                int p = i ^ j;
                if (p > i) {
                    float a = srt[i], c = srt[p];
                    bool up = ((i & k) == 0);
                    if (up ? (a < c) : (a > c)) { srt[i] = c; srt[p] = a; }
                }
            }
            __syncthreads();
        }
    }

    // inclusive scan of srt and srt^2 (2 elems/thread + Hillis-Steele)
    float e0 = srt[2 * t], e1 = srt[2 * t + 1];
    sp[t] = e0 + e1;
    sq[t] = e0 * e0 + e1 * e1;
    __syncthreads();
    for (int off = 1; off < 1024; off <<= 1) {
        float ap = 0.f, aq = 0.f;
        if (t >= off) { ap = sp[t - off]; aq = sq[t - off]; }
        __syncthreads();
        sp[t] += ap; sq[t] += aq;
        __syncthreads();
    }
    float excl_p = (t > 0) ? sp[t - 1] : 0.f;
    float excl_q = (t > 0) ? sq[t - 1] : 0.f;

    int cnt_local = 0;
    float tau0, tau1;
    {
        float c0  = excl_p + e0;
        float c0q = excl_q + e0 * e0;
        float rho = (float)(2 * t + 1);
        float mean   = c0 / rho;
        float meansq = c0q / rho;
        float ssv    = rho * (meansq - mean * mean);
        float delta  = (1.f - ssv) / rho;
        tau0 = mean - sqrtf(fmaxf(delta, 0.f));
        cnt_local += (tau0 <= e0) ? 1 : 0;

        float c1  = c0 + e1;
        float c1q = c0q + e1 * e1;
        rho = (float)(2 * t + 2);
        mean   = c1 / rho;
        meansq = c1q / rho;
        ssv    = rho * (meansq - mean * mean);
        delta  = (1.f - ssv) / rho;
        tau1 = mean - sqrtf(fmaxf(delta, 0.f));
        cnt_local += (tau1 <= e1) ? 1 : 0;
    }
    tau[2 * t]     = tau0;
    tau[2 * t + 1] = tau1;
    if (t == 0) s_cnt = 0;
    __syncthreads();

    int c = cnt_local;
    #pragma unroll
    for (int off = 32; off > 0; off >>= 1) c += __shfl_down(c, off, 64);
    if ((t & 63) == 0) atomicAdd(&s_cnt, c);
    __syncthreads();
    if (t == 0) s_taustar = tau[s_cnt - 1];
    __syncthreads();
    float ts = s_taustar;

    float w0 = fmaxf(s_orig[t] - ts, 0.f);
    float w1 = fmaxf(s_orig[t + 1024] - ts, 0.f);
    weights[(size_t)b * SS + t]        = w0 * w0;
    weights[(size_t)b * SS + t + 1024] = w1 * w1;
}

// ---------------------------------------------------------------------------
// Kernel 3: context[b,h] = sum_s X[b,s,h] * w[b,s], skipping w==0 rows.
// grid (16 s-chunks, 64 batches) x 256 threads; each thread owns h and h+256.
// ---------------------------------------------------------------------------
__global__ __launch_bounds__(256) void context_kernel(
    const float* __restrict__ X, const float* __restrict__ weights,
    float* __restrict__ ctx)
{
    const int b = blockIdx.y;
    const int chunk = blockIdx.x;         // 0..15, 128 s each
    const int tid = threadIdx.x;
    const float* wrow  = weights + (size_t)b * SS + chunk * 128;
    const float* xbase = X + ((size_t)b * SS + (size_t)chunk * 128) * HH;
    float acc0 = 0.f, acc1 = 0.f;
    bool any = false;
    for (int s = 0; s < 128; s++) {
        float w = wrow[s];
        if (w != 0.f) {                    // block-uniform branch
            any = true;
            const float* xr = xbase + (size_t)s * HH;
            acc0 = fmaf(xr[tid],       w, acc0);
            acc1 = fmaf(xr[tid + 256], w, acc1);
        }
    }
    if (any) {
        atomicAdd(&ctx[b * HH + tid],       acc0);
        atomicAdd(&ctx[b * HH + tid + 256], acc1);
    }
}

// ---------------------------------------------------------------------------
extern "C" void kernel_launch(void* const* d_in, const int* in_sizes, int n_in,
                              void* d_out, int out_size, void* d_ws, size_t ws_size,
                              hipStream_t stream) {
    const float* X  = (const float*)d_in[0];   // [64,2048,512]
    const float* W1 = (const float*)d_in[1];   // [512,128]
    const float* b1 = (const float*)d_in[2];   // [128]
    const float* W2 = (const float*)d_in[3];   // [128,1]
    const float* b2 = (const float*)d_in[4];   // [1]

    float* out     = (float*)d_out;
    float* ctx     = out;                      // [64,512]
    float* weights = out + BB * HH;            // [64,2048]
    // Stage scores in the weights output region (same size; kernel 2 reads
    // its row fully before writing it). No dependence on ws_size.
    float* scores  = weights;

    hipMemsetAsync(ctx, 0, (size_t)BB * HH * sizeof(float), stream);
    score_kernel<<<dim3(MM / 128), 256, 0, stream>>>(X, W1, b1, W2, b2, scores);
    entmax_kernel<<<dim3(BB), 1024, 0, stream>>>(scores, weights);
    context_kernel<<<dim3(16, BB), 256, 0, stream>>>(X, weights, ctx);
}

// Round 2
// 424.382 us; speedup vs baseline: 1.4538x; 1.4538x over previous
//
#include <hip/hip_runtime.h>
#include <math.h>

#define BB 64
#define SS 2048
#define HH 512
#define AA 128
#define MM (BB*SS)
#define BM 128   // rows per score block

typedef __attribute__((ext_vector_type(8)))  short short8;
typedef __attribute__((ext_vector_type(16))) float f32x16;

__device__ inline unsigned short f2bf(float f) {
    unsigned u = __float_as_uint(f);
    unsigned r = (u + 0x7fff + ((u >> 16) & 1)) >> 16;
    return (unsigned short)r;
}
__device__ inline float bf2f(unsigned short h) {
    return __uint_as_float(((unsigned)h) << 16);
}

// ---------------------------------------------------------------------------
// Kernel 0: W1 [512,128] fp32 -> W1T hi/lo bf16 [128,512] in d_ws.
// ---------------------------------------------------------------------------
__global__ __launch_bounds__(256) void prep_w1t(
    const float* __restrict__ W1, unsigned short* __restrict__ W1Th,
    unsigned short* __restrict__ W1Tl)
{
    int idx = blockIdx.x * 256 + threadIdx.x;   // 65536
    int n = idx & 127, k = idx >> 7;
    float v = W1[k * AA + n];
    unsigned short h = f2bf(v);
    W1Th[n * HH + k] = h;
    W1Tl[n * HH + k] = f2bf(v - bf2f(h));
}

// ---------------------------------------------------------------------------
// Kernel 1: scores = tanh(X@W1+b1)@W2+b2 via split-bf16 MFMA.
// Block: 256 thr = 4 waves; block tile 128(M) x 128(N); wave = 32M x 128N
// = 4 tiles of 32x32 (mfma_f32_32x32x16_bf16), 3 split products each.
// LDS: [hilo][g(k8-group)][row][8k] 16B chunks, lane-consecutive = no conflicts.
// ---------------------------------------------------------------------------
__global__ __launch_bounds__(256) void score_mfma(
    const float* __restrict__ X,
    const unsigned short* __restrict__ W1Th,
    const unsigned short* __restrict__ W1Tl,
    const float* __restrict__ b1, const float* __restrict__ W2,
    const float* __restrict__ b2, float* __restrict__ scores)
{
    __shared__ unsigned short A_lds[2][4][BM][8];   // 16 KB
    __shared__ unsigned short B_lds[2][4][AA][8];   // 16 KB

    const int tid  = threadIdx.x;
    const int wave = tid >> 6;
    const int lane = tid & 63;
    const int l31  = lane & 31;
    const int half = lane >> 5;
    const int m0   = blockIdx.x * BM;

    f32x16 acc[4];
    #pragma unroll
    for (int nt = 0; nt < 4; nt++)
        #pragma unroll
        for (int j = 0; j < 16; j++) acc[nt][j] = 0.f;

    for (int k0 = 0; k0 < HH; k0 += 32) {
        // ---- stage A: 128 rows x 32 k, fp32 -> hi/lo bf16
        const int kq = tid & 7;           // float4 index within 32 k
        const int g  = kq >> 1;           // k8-group 0..3
        const int jo = (kq & 1) * 4;      // offset within 8k chunk
        #pragma unroll
        for (int i = 0; i < 4; i++) {
            int m = (tid >> 3) + 32 * i;
            float4 f = *(const float4*)(X + (size_t)(m0 + m) * HH + k0 + kq * 4);
            unsigned short h0 = f2bf(f.x), h1 = f2bf(f.y),
                           h2 = f2bf(f.z), h3 = f2bf(f.w);
            ushort4 hv = {h0, h1, h2, h3};
            ushort4 lv = {f2bf(f.x - bf2f(h0)), f2bf(f.y - bf2f(h1)),
                          f2bf(f.z - bf2f(h2)), f2bf(f.w - bf2f(h3))};
            int msw = m ^ (g << 1);       // bank swizzle
            *(ushort4*)&A_lds[0][g][msw][jo] = hv;
            *(ushort4*)&A_lds[1][g][msw][jo] = lv;
        }
        // ---- stage B: 32 k x 128 n from pre-split W1T (16B chunks)
        #pragma unroll
        for (int i = 0; i < 4; i++) {
            int c    = tid + 256 * i;     // 0..1023 chunks
            int hilo = c >> 9;
            int gg   = (c >> 7) & 3;
            int n    = c & 127;
            const unsigned short* src = hilo ? W1Tl : W1Th;
            short8 v = *(const short8*)(src + (size_t)n * HH + k0 + gg * 8);
            *(short8*)&B_lds[hilo][gg][n][0] = v;
        }
        __syncthreads();

        #pragma unroll
        for (int s = 0; s < 2; s++) {
            int gr  = s * 2 + half;
            int mr  = wave * 32 + l31;
            short8 a_h = *(const short8*)&A_lds[0][gr][mr ^ (gr << 1)][0];
            short8 a_l = *(const short8*)&A_lds[1][gr][mr ^ (gr << 1)][0];
            #pragma unroll
            for (int nt = 0; nt < 4; nt++) {
                int nr = nt * 32 + l31;
                short8 b_h = *(const short8*)&B_lds[0][gr][nr][0];
                short8 b_l = *(const short8*)&B_lds[1][gr][nr][0];
                acc[nt] = __builtin_amdgcn_mfma_f32_32x32x16_bf16(a_h, b_h, acc[nt], 0, 0, 0);
                acc[nt] = __builtin_amdgcn_mfma_f32_32x32x16_bf16(a_h, b_l, acc[nt], 0, 0, 0);
                acc[nt] = __builtin_amdgcn_mfma_f32_32x32x16_bf16(a_l, b_h, acc[nt], 0, 0, 0);
            }
        }
        __syncthreads();
    }

    // ---- epilogue: tanh + dot(W2) fused; reduce cols across 32 lanes
    float part[16];
    #pragma unroll
    for (int r = 0; r < 16; r++) part[r] = 0.f;
    #pragma unroll
    for (int nt = 0; nt < 4; nt++) {
        int n = nt * 32 + l31;
        float bias = b1[n];
        float w2   = W2[n];
        #pragma unroll
        for (int r = 0; r < 16; r++)
            part[r] += tanhf(acc[nt][r] + bias) * w2;
    }
    #pragma unroll
    for (int off = 16; off > 0; off >>= 1)
        #pragma unroll
        for (int r = 0; r < 16; r++)
            part[r] += __shfl_xor(part[r], off);
    if (l31 == 0) {
        float bb2 = b2[0];
        #pragma unroll
        for (int r = 0; r < 16; r++) {
            int row = (r & 3) + 8 * (r >> 2) + 4 * half;
            scores[m0 + wave * 32 + row] = part[r] + bb2;
        }
    }
}

// ---------------------------------------------------------------------------
// Kernel 2: exact entmax-1.5 over S=2048 per batch (one block per batch).
// scores may alias the weights output: fully read before any write.
// ---------------------------------------------------------------------------
__global__ __launch_bounds__(1024) void entmax_kernel(
    const float* __restrict__ scores, float* __restrict__ weights)
{
    __shared__ float s_orig[SS];
    __shared__ float srt[SS];
    __shared__ float tau[SS];
    __shared__ float sp[1024];
    __shared__ float sq[1024];
    __shared__ float red[16];
    __shared__ int   s_cnt;
    __shared__ float s_max, s_taustar;

    const int t = threadIdx.x;
    const int b = blockIdx.x;
    const float* row = scores + (size_t)b * SS;

    float v0 = row[t];
    float v1 = row[t + 1024];

    float mx = fmaxf(v0, v1);
    #pragma unroll
    for (int off = 32; off > 0; off >>= 1)
        mx = fmaxf(mx, __shfl_down(mx, off, 64));
    if ((t & 63) == 0) red[t >> 6] = mx;
    __syncthreads();
    if (t < 16) {
        float m = red[t];
        #pragma unroll
        for (int off = 8; off > 0; off >>= 1)
            m = fmaxf(m, __shfl_down(m, off, 16));
        if (t == 0) s_max = m;
    }
    __syncthreads();
    mx = s_max;
    v0 = (v0 - mx) * 0.5f;
    v1 = (v1 - mx) * 0.5f;
    s_orig[t]        = v0;
    s_orig[t + 1024] = v1;
    srt[t]           = v0;
    srt[t + 1024]    = v1;
    __syncthreads();

    for (int k = 2; k <= SS; k <<= 1) {
        for (int j = k >> 1; j > 0; j >>= 1) {
            #pragma unroll
            for (int u = 0; u < 2; u++) {
                int i = t + 1024 * u;
                int p = i ^ j;
                if (p > i) {
                    float a = srt[i], c = srt[p];
                    bool up = ((i & k) == 0);
                    if (up ? (a < c) : (a > c)) { srt[i] = c; srt[p] = a; }
                }
            }
            __syncthreads();
        }
    }

    float e0 = srt[2 * t], e1 = srt[2 * t + 1];
    sp[t] = e0 + e1;
    sq[t] = e0 * e0 + e1 * e1;
    __syncthreads();
    for (int off = 1; off < 1024; off <<= 1) {
        float ap = 0.f, aq = 0.f;
        if (t >= off) { ap = sp[t - off]; aq = sq[t - off]; }
        __syncthreads();
        sp[t] += ap; sq[t] += aq;
        __syncthreads();
    }
    float excl_p = (t > 0) ? sp[t - 1] : 0.f;
    float excl_q = (t > 0) ? sq[t - 1] : 0.f;

    int cnt_local = 0;
    float tau0, tau1;
    {
        float c0  = excl_p + e0;
        float c0q = excl_q + e0 * e0;
        float rho = (float)(2 * t + 1);
        float mean   = c0 / rho;
        float meansq = c0q / rho;
        float ssv    = rho * (meansq - mean * mean);
        float delta  = (1.f - ssv) / rho;
        tau0 = mean - sqrtf(fmaxf(delta, 0.f));
        cnt_local += (tau0 <= e0) ? 1 : 0;

        float c1  = c0 + e1;
        float c1q = c0q + e1 * e1;
        rho = (float)(2 * t + 2);
        mean   = c1 / rho;
        meansq = c1q / rho;
        ssv    = rho * (meansq - mean * mean);
        delta  = (1.f - ssv) / rho;
        tau1 = mean - sqrtf(fmaxf(delta, 0.f));
        cnt_local += (tau1 <= e1) ? 1 : 0;
    }
    tau[2 * t]     = tau0;
    tau[2 * t + 1] = tau1;
    if (t == 0) s_cnt = 0;
    __syncthreads();

    int c = cnt_local;
    #pragma unroll
    for (int off = 32; off > 0; off >>= 1) c += __shfl_down(c, off, 64);
    if ((t & 63) == 0) atomicAdd(&s_cnt, c);
    __syncthreads();
    if (t == 0) s_taustar = tau[s_cnt - 1];
    __syncthreads();
    float ts = s_taustar;

    float w0 = fmaxf(s_orig[t] - ts, 0.f);
    float w1 = fmaxf(s_orig[t + 1024] - ts, 0.f);
    weights[(size_t)b * SS + t]        = w0 * w0;
    weights[(size_t)b * SS + t + 1024] = w1 * w1;
}

// ---------------------------------------------------------------------------
// Kernel 3: context[b,h] = sum_s X[b,s,h]*w[b,s], skipping w==0 rows.
// grid (32 s-chunks, 64 b) x 256 thr; thread owns h=2t,2t+1 (float2 loads).
// ---------------------------------------------------------------------------
__global__ __launch_bounds__(256) void context_kernel(
    const float* __restrict__ X, const float* __restrict__ weights,
    float* __restrict__ ctx)
{
    const int b = blockIdx.y;
    const int chunk = blockIdx.x;         // 0..31, 64 s each
    const int tid = threadIdx.x;
    const float* wrow  = weights + (size_t)b * SS + chunk * 64;
    const float* xbase = X + ((size_t)b * SS + (size_t)chunk * 64) * HH;
    float acc0 = 0.f, acc1 = 0.f;
    bool any = false;
    for (int s = 0; s < 64; s++) {
        float w = wrow[s];
        if (w != 0.f) {
            any = true;
            float2 x = *(const float2*)(xbase + (size_t)s * HH + 2 * tid);
            acc0 = fmaf(x.x, w, acc0);
            acc1 = fmaf(x.y, w, acc1);
        }
    }
    if (any) {
        atomicAdd(&ctx[b * HH + 2 * tid],     acc0);
        atomicAdd(&ctx[b * HH + 2 * tid + 1], acc1);
    }
}

// ---------------------------------------------------------------------------
extern "C" void kernel_launch(void* const* d_in, const int* in_sizes, int n_in,
                              void* d_out, int out_size, void* d_ws, size_t ws_size,
                              hipStream_t stream) {
    const float* X  = (const float*)d_in[0];   // [64,2048,512]
    const float* W1 = (const float*)d_in[1];   // [512,128]
    const float* b1 = (const float*)d_in[2];   // [128]
    const float* W2 = (const float*)d_in[3];   // [128,1]
    const float* b2 = (const float*)d_in[4];   // [1]

    float* out     = (float*)d_out;
    float* ctx     = out;                      // [64,512]
    float* weights = out + BB * HH;            // [64,2048]
    float* scores  = weights;                  // staged in weights region

    unsigned short* W1Th = (unsigned short*)d_ws;           // 128 KB
    unsigned short* W1Tl = W1Th + (size_t)AA * HH;          // 128 KB

    hipMemsetAsync(ctx, 0, (size_t)BB * HH * sizeof(float), stream);
    prep_w1t<<<dim3(256), 256, 0, stream>>>(W1, W1Th, W1Tl);
    score_mfma<<<dim3(MM / BM), 256, 0, stream>>>(X, W1Th, W1Tl, b1, W2, b2, scores);
    entmax_kernel<<<dim3(BB), 1024, 0, stream>>>(scores, weights);
    context_kernel<<<dim3(32, BB), 256, 0, stream>>>(X, weights, ctx);
}

// Round 3
// 403.190 us; speedup vs baseline: 1.5302x; 1.0526x over previous
//
#include <hip/hip_runtime.h>
#include <math.h>

#define BB 64
#define SS 2048
#define HH 512
#define AA 128
#define MM (BB*SS)

typedef __attribute__((ext_vector_type(8)))  short short8;
typedef __attribute__((ext_vector_type(16))) float f32x16;

__device__ inline unsigned short f2bf_rne(float f) {
    unsigned u = __float_as_uint(f);
    unsigned r = (u + 0x7fff + ((u >> 16) & 1)) >> 16;
    return (unsigned short)r;
}
__device__ inline float bf2f(unsigned short h) {
    return __uint_as_float(((unsigned)h) << 16);
}
__device__ inline float fast_tanh(float x) {
    // tanh(x) = 1 - 2/(e^{2x}+1); exact at +/-inf saturation, abs err ~1e-7
    float t = __expf(2.0f * x);
    return 1.0f - 2.0f * __builtin_amdgcn_rcpf(t + 1.0f);
}

// ---------------------------------------------------------------------------
// Kernel 0: W1 [512,128] fp32 -> W1T hi/lo bf16 [128,512] in d_ws.
// ---------------------------------------------------------------------------
__global__ __launch_bounds__(256) void prep_w1t(
    const float* __restrict__ W1, unsigned short* __restrict__ W1Th,
    unsigned short* __restrict__ W1Tl)
{
    int idx = blockIdx.x * 256 + threadIdx.x;   // 65536
    int n = idx & 127, k = idx >> 7;
    float v = W1[k * AA + n];
    unsigned short h = f2bf_rne(v);
    W1Th[n * HH + k] = h;
    W1Tl[n * HH + k] = f2bf_rne(v - bf2f(h));
}

// ---------------------------------------------------------------------------
// Kernel 1: scores = tanh(X@W1+b1)@W2+b2, split-bf16 MFMA (3 products).
// 256 thr = 4 waves; block = 256 M rows; wave = 64 M (2 m-tiles) x 128 N.
// A fragments: direct global gather + in-register hi/lo split (no LDS).
// B: double-buffered LDS, one barrier per k-iteration.
// ---------------------------------------------------------------------------
__global__ __launch_bounds__(256, 2) void score_mfma(
    const float* __restrict__ X,
    const unsigned short* __restrict__ W1Th,
    const unsigned short* __restrict__ W1Tl,
    const float* __restrict__ b1, const float* __restrict__ W2,
    const float* __restrict__ b2, float* __restrict__ scores)
{
    __shared__ unsigned short B_lds[2][2][4][AA][8];   // [buf][hilo][gr][n][8k] 32 KB

    const int tid  = threadIdx.x;
    const int wave = tid >> 6;
    const int lane = tid & 63;
    const int l31  = lane & 31;
    const int half = lane >> 5;
    const int m0   = blockIdx.x * 256;

    // B staging thread-constant indices (4 chunks per thread)
    int sb_hilo[4], sb_g[4], sb_n[4];
    #pragma unroll
    for (int i = 0; i < 4; i++) {
        int c = tid + 256 * i;
        sb_hilo[i] = c >> 9;
        sb_g[i]    = (c >> 7) & 3;
        sb_n[i]    = c & 127;
    }

    // A row base pointers (per m-tile), offset by half*8 k
    const float* aptr0 = X + (size_t)(m0 + wave * 64      + l31) * HH + half * 8;
    const float* aptr1 = X + (size_t)(m0 + wave * 64 + 32 + l31) * HH + half * 8;

    f32x16 acc[2][4];
    #pragma unroll
    for (int mt = 0; mt < 2; mt++)
        #pragma unroll
        for (int nt = 0; nt < 4; nt++)
            #pragma unroll
            for (int j = 0; j < 16; j++) acc[mt][nt][j] = 0.f;

    short8 breg[4];
    float4 apre[2][2][2];   // [mt][s][j-half]

    // ---- preload iter 0
    #pragma unroll
    for (int i = 0; i < 4; i++) {
        const unsigned short* src = sb_hilo[i] ? W1Tl : W1Th;
        breg[i] = *(const short8*)(src + (size_t)sb_n[i] * HH + sb_g[i] * 8);
    }
    #pragma unroll
    for (int s = 0; s < 2; s++) {
        apre[0][s][0] = *(const float4*)(aptr0 + s * 16);
        apre[0][s][1] = *(const float4*)(aptr0 + s * 16 + 4);
        apre[1][s][0] = *(const float4*)(aptr1 + s * 16);
        apre[1][s][1] = *(const float4*)(aptr1 + s * 16 + 4);
    }
    #pragma unroll
    for (int i = 0; i < 4; i++)
        *(short8*)&B_lds[0][sb_hilo[i]][sb_g[i]][sb_n[i]][0] = breg[i];
    __syncthreads();

    for (int it = 0; it < 16; it++) {
        const int cur = it & 1;

        // issue B global loads for next iter
        if (it < 15) {
            #pragma unroll
            for (int i = 0; i < 4; i++) {
                const unsigned short* src = sb_hilo[i] ? W1Tl : W1Th;
                breg[i] = *(const short8*)(src + (size_t)sb_n[i] * HH
                                           + (it + 1) * 32 + sb_g[i] * 8);
            }
        }

        // convert A fragments (hi RNE / lo trunc split)
        short8 ah[2][2], al[2][2];
        #pragma unroll
        for (int mt = 0; mt < 2; mt++)
            #pragma unroll
            for (int s = 0; s < 2; s++) {
                float fs[8];
                *(float4*)&fs[0] = apre[mt][s][0];
                *(float4*)&fs[4] = apre[mt][s][1];
                #pragma unroll
                for (int j = 0; j < 8; j++) {
                    unsigned short h = f2bf_rne(fs[j]);
                    ah[mt][s][j] = (short)h;
                    float r = fs[j] - bf2f(h);
                    al[mt][s][j] = (short)(__float_as_uint(r) >> 16);
                }
            }

        // issue A global loads for next iter (regs now free)
        if (it < 15) {
            #pragma unroll
            for (int s = 0; s < 2; s++) {
                apre[0][s][0] = *(const float4*)(aptr0 + (it + 1) * 32 + s * 16);
                apre[0][s][1] = *(const float4*)(aptr0 + (it + 1) * 32 + s * 16 + 4);
                apre[1][s][0] = *(const float4*)(aptr1 + (it + 1) * 32 + s * 16);
                apre[1][s][1] = *(const float4*)(aptr1 + (it + 1) * 32 + s * 16 + 4);
            }
        }

        // MFMA: B frag reused across 2 m-tiles
        #pragma unroll
        for (int s = 0; s < 2; s++) {
            const int gr = s * 2 + half;
            #pragma unroll
            for (int nt = 0; nt < 4; nt++) {
                short8 bh = *(const short8*)&B_lds[cur][0][gr][nt * 32 + l31][0];
                short8 bl = *(const short8*)&B_lds[cur][1][gr][nt * 32 + l31][0];
                acc[0][nt] = __builtin_amdgcn_mfma_f32_32x32x16_bf16(ah[0][s], bh, acc[0][nt], 0, 0, 0);
                acc[0][nt] = __builtin_amdgcn_mfma_f32_32x32x16_bf16(ah[0][s], bl, acc[0][nt], 0, 0, 0);
                acc[0][nt] = __builtin_amdgcn_mfma_f32_32x32x16_bf16(al[0][s], bh, acc[0][nt], 0, 0, 0);
                acc[1][nt] = __builtin_amdgcn_mfma_f32_32x32x16_bf16(ah[1][s], bh, acc[1][nt], 0, 0, 0);
                acc[1][nt] = __builtin_amdgcn_mfma_f32_32x32x16_bf16(ah[1][s], bl, acc[1][nt], 0, 0, 0);
                acc[1][nt] = __builtin_amdgcn_mfma_f32_32x32x16_bf16(al[1][s], bh, acc[1][nt], 0, 0, 0);
            }
        }

        // write next-iter B to the other buffer
        if (it < 15) {
            #pragma unroll
            for (int i = 0; i < 4; i++)
                *(short8*)&B_lds[cur ^ 1][sb_hilo[i]][sb_g[i]][sb_n[i]][0] = breg[i];
        }
        __syncthreads();
    }

    // ---- epilogue: tanh + dot(W2); reduce cols across 32 lanes
    const float bb2 = b2[0];
    #pragma unroll
    for (int mt = 0; mt < 2; mt++) {
        float part[16];
        #pragma unroll
        for (int r = 0; r < 16; r++) part[r] = 0.f;
        #pragma unroll
        for (int nt = 0; nt < 4; nt++) {
            int n = nt * 32 + l31;
            float bias = b1[n];
            float w2   = W2[n];
            #pragma unroll
            for (int r = 0; r < 16; r++)
                part[r] += fast_tanh(acc[mt][nt][r] + bias) * w2;
        }
        #pragma unroll
        for (int off = 16; off > 0; off >>= 1)
            #pragma unroll
            for (int r = 0; r < 16; r++)
                part[r] += __shfl_xor(part[r], off);
        if (l31 == 0) {
            #pragma unroll
            for (int r = 0; r < 16; r++) {
                int row = (r & 3) + 8 * (r >> 2) + 4 * half;
                scores[m0 + wave * 64 + mt * 32 + row] = part[r] + bb2;
            }
        }
    }
}

// ---------------------------------------------------------------------------
// Kernel 2: exact entmax-1.5 via bisection on sum(max(s-tau,0)^2) = 1.
// One block (256 thr) per batch row; root bracket [-1, 0]; 32 iterations.
// scores aliases weights output: fully read into regs before any write.
// ---------------------------------------------------------------------------
__global__ __launch_bounds__(256) void entmax_bisect(
    const float* __restrict__ scores, float* __restrict__ weights)
{
    __shared__ float red[4];
    const int t = threadIdx.x, b = blockIdx.x;
    const int wv = t >> 6, ln = t & 63;
    const float* row = scores + (size_t)b * SS;

    float v[8];
    #pragma unroll
    for (int i = 0; i < 8; i++) v[i] = row[t + 256 * i];

    // block max
    float mx = v[0];
    #pragma unroll
    for (int i = 1; i < 8; i++) mx = fmaxf(mx, v[i]);
    #pragma unroll
    for (int off = 32; off > 0; off >>= 1) mx = fmaxf(mx, __shfl_xor(mx, off));
    if (ln == 0) red[wv] = mx;
    __syncthreads();
    mx = fmaxf(fmaxf(red[0], red[1]), fmaxf(red[2], red[3]));

    #pragma unroll
    for (int i = 0; i < 8; i++) v[i] = (v[i] - mx) * 0.5f;

    float lo = -1.0f, hi = 0.0f;
    for (int it = 0; it < 32; it++) {
        float tm = 0.5f * (lo + hi);
        float s = 0.f;
        #pragma unroll
        for (int i = 0; i < 8; i++) {
            float d = fmaxf(v[i] - tm, 0.f);
            s = fmaf(d, d, s);
        }
        #pragma unroll
        for (int off = 32; off > 0; off >>= 1) s += __shfl_xor(s, off);
        __syncthreads();                 // protect red[] reuse
        if (ln == 0) red[wv] = s;
        __syncthreads();
        s = red[0] + red[1] + red[2] + red[3];
        if (s >= 1.0f) lo = tm; else hi = tm;   // uniform branch
    }
    float tau = 0.5f * (lo + hi);

    #pragma unroll
    for (int i = 0; i < 8; i++) {
        float d = fmaxf(v[i] - tau, 0.f);
        weights[(size_t)b * SS + t + 256 * i] = d * d;
    }
}

// ---------------------------------------------------------------------------
// Kernel 3: context[b,h] = sum_s X[b,s,h]*w[b,s], skipping w==0 rows.
// ---------------------------------------------------------------------------
__global__ __launch_bounds__(256) void context_kernel(
    const float* __restrict__ X, const float* __restrict__ weights,
    float* __restrict__ ctx)
{
    const int b = blockIdx.y;
    const int chunk = blockIdx.x;         // 0..31, 64 s each
    const int tid = threadIdx.x;
    const float* wrow  = weights + (size_t)b * SS + chunk * 64;
    const float* xbase = X + ((size_t)b * SS + (size_t)chunk * 64) * HH;
    float acc0 = 0.f, acc1 = 0.f;
    bool any = false;
    for (int s = 0; s < 64; s++) {
        float w = wrow[s];
        if (w != 0.f) {
            any = true;
            float2 x = *(const float2*)(xbase + (size_t)s * HH + 2 * tid);
            acc0 = fmaf(x.x, w, acc0);
            acc1 = fmaf(x.y, w, acc1);
        }
    }
    if (any) {
        atomicAdd(&ctx[b * HH + 2 * tid],     acc0);
        atomicAdd(&ctx[b * HH + 2 * tid + 1], acc1);
    }
}

// ---------------------------------------------------------------------------
extern "C" void kernel_launch(void* const* d_in, const int* in_sizes, int n_in,
                              void* d_out, int out_size, void* d_ws, size_t ws_size,
                              hipStream_t stream) {
    const float* X  = (const float*)d_in[0];   // [64,2048,512]
    const float* W1 = (const float*)d_in[1];   // [512,128]
    const float* b1 = (const float*)d_in[2];   // [128]
    const float* W2 = (const float*)d_in[3];   // [128,1]
    const float* b2 = (const float*)d_in[4];   // [1]

    float* out     = (float*)d_out;
    float* ctx     = out;                      // [64,512]
    float* weights = out + BB * HH;            // [64,2048]
    float* scores  = weights;                  // staged in weights region

    unsigned short* W1Th = (unsigned short*)d_ws;           // 128 KB
    unsigned short* W1Tl = W1Th + (size_t)AA * HH;          // 128 KB

    hipMemsetAsync(ctx, 0, (size_t)BB * HH * sizeof(float), stream);
    prep_w1t<<<dim3(256), 256, 0, stream>>>(W1, W1Th, W1Tl);
    score_mfma<<<dim3(MM / 256), 256, 0, stream>>>(X, W1Th, W1Tl, b1, W2, b2, scores);
    entmax_bisect<<<dim3(BB), 256, 0, stream>>>(scores, weights);
    context_kernel<<<dim3(32, BB), 256, 0, stream>>>(X, weights, ctx);
}